// Round 4
// baseline (387.094 us; speedup 1.0000x reference)
//
#include <hip/hip_runtime.h>

// ---------------------------------------------------------------------------
// ConvCaps (EM routing): b=8, B=32, C=32, K=3, stride=2, Win=13, Wout=6, 3 iters
// x: (8, 544, 13, 13) f32   [pose 512ch = (q,r,o), act 32ch]
// W: (3,3,32,32,4,4) f32    [ch=(ij*32+o)][c][p][q], 512 floats per ch
// out: (8, 544, 6, 6) f32
// vote[d=p*4+r] = sum_q W[ch][c][p][q] * pose[n,q,r,o, 2x+i, 2y+j]
//
// R14 = R13 structure (512-thr/8-wave blocks, shared sP stage, grid 1152,
// (512,4)) with EXPLICIT 1-DEEP SOFTWARE PIPELINING of the M and E k-loops.
// Evidence: R11 (20 waves/CU) == R13 (32 waves/CU) == ~155-159 us refutes
// TLP as the lever; VALU/L1/LDS all ~15-30% busy -> intra-wave serial
// latency. At 60 VGPR the compiler can't prefetch (5 iters x 32 regs in
// flight needed); emitted code is load->wait->compute per k (~4500 cyc
// serial/wave). Fix: double-buffer W,P,sE across k in M and E loops
// (named regs, static indexing per rule #20), and issue E's k=0 loads
// before the 33-DPP-reduction block (~600 reg-only cycles to hide under).
// VGPR ~60 -> ~110 (under 128 cap, no spill expected; spill -> WRITE_SIZE
// blowup like R12, fallback = drop E-prologue prefetch).
// Session rules: hard occupancy bounds that push VGPR < ~60 -> catastrophic
// spill (R12). Occupancy 20 vs 32 waves/CU: neutral (R13).
// p_hat slices are block-private; only D crosses blocks -> ping-pong D0/D1.
// ---------------------------------------------------------------------------

typedef float v2f __attribute__((ext_vector_type(2)));
typedef float v4f __attribute__((ext_vector_type(4)));

// workspace layout (floats)
#define OFF_PHAT 0           // 288*32*288 = 2654208   [spatial][c][slot]
#define OFF_D0   2654208     // 43264 = 8*169*32   [n][pix][o]
#define OFF_D1   2697472     // 43264
#define OFF_POST 2740736     // 692224 = 8*32*169*16   [(n,o)][pix][d]
#define OFF_ACTT 3432960     // 43264  [n][pix][o]
#define OFF_WT2  3476224     // 147456 = 32*288*16  [c][ch][d]
// total 3623680 floats = 14.5 MB

// DPP butterfly-reduce on the VALU pipe (no DS-pipe traffic).
template <int CTRL>
__device__ __forceinline__ float dppadd(float v) {
  int p = __builtin_amdgcn_update_dpp(0, __float_as_int(v), CTRL, 0xF, 0xF, true);
  return v + __int_as_float(p);
}

__device__ __forceinline__ float wsum64(float v) {
  v = dppadd<0xB1>(v);    // quad_perm {1,0,3,2}  : xor 1
  v = dppadd<0x4E>(v);    // quad_perm {2,3,0,1}  : xor 2
  v = dppadd<0x141>(v);   // row_half_mirror      : xor 7  -> 8-lane sums
  v = dppadd<0x140>(v);   // row_mirror           : xor 15 -> row (16) sums
  v = dppadd<0x142>(v);   // row_bcast15: row1 += row0, row3 += row2
  v = dppadd<0x143>(v);   // row_bcast31: rows 2,3 += (row0+row1); lane63 = total
  return __int_as_float(__builtin_amdgcn_readlane(__float_as_int(v), 63));
}

__device__ __forceinline__ v2f lo2(v4f a) { return __builtin_shufflevector(a, a, 0, 1); }
__device__ __forceinline__ v2f hi2(v4f a) { return __builtin_shufflevector(a, a, 2, 3); }

// One fused prep kernel (range-branched elementwise):
//   [0,692224)        pose transpose -> posT[((n*32+o)*169+pix)*16 + d]
//   [692224,735488)   act transpose  -> actT[n][pix][o]
//   [735488,882944)   W transpose    -> Wt2[c][ch][d]
//   [882944,969472)   zero D0 and D1
__global__ __launch_bounds__(256) void prep_kernel(
    const float* __restrict__ x, const float* __restrict__ Wt,
    float* __restrict__ posT, float* __restrict__ actT,
    float* __restrict__ Wt2, float* __restrict__ Dz) {
  int tid = blockIdx.x * 256 + threadIdx.x;   // 969472 = 3787*256
  if (tid < 692224) {
    int pix = tid % 169; int t = tid / 169;
    int o = t & 31; t >>= 5;
    int d = t & 15; int n = t >> 4;
    float v = x[((size_t)n * 544 + d * 32 + o) * 169 + pix];
    posT[((size_t)(n * 32 + o) * 169 + pix) * 16 + d] = v;
  } else if (tid < 735488) {
    int r = tid - 692224;
    int pix = r % 169; int t = r / 169;
    int o = t & 31; int n = t >> 5;
    float v = x[(size_t)n * 91936 + 86528 + o * 169 + pix];
    actT[((size_t)n * 169 + pix) * 32 + o] = v;
  } else if (tid < 882944) {
    int r = tid - 735488;                     // 147456 = 32*288*16
    int c = r / 4608; int s = r - c * 4608;
    int ch = s >> 4, d = s & 15;
    Wt2[r] = Wt[(size_t)ch * 512 + c * 16 + d];
  } else {
    Dz[tid - 882944] = 0.f;                   // D0 then D1 (contiguous)
  }
}

// Fused EM step. 512 threads = 8 waves, one c per wave (8 c's per block).
// mode 0: M(uniform Rp) + E -> p_hat, Dwrite
// mode 1: M(p_hat, Dread) + E -> p_hat, Dwrite
// mode 2: M(p_hat, Dread) -> final output
__global__ __launch_bounds__(512, 4) void em_kernel(
    const float* __restrict__ Wt2, const float* __restrict__ posT,
    const float* __restrict__ actT, float* __restrict__ p_hat,
    const float* __restrict__ Dread, float* __restrict__ Dwrite,
    const float* __restrict__ beta_v, const float* __restrict__ beta_a,
    const float* __restrict__ lambda_, float* __restrict__ out, int mode) {
  __shared__ float sP[288 * 20];   // pose patch, stride 20 (float4-aligned)
  __shared__ float sE[288];        // a/1152 or a/D per child slot
  __shared__ float sPh[8 * 288];   // per-wave p_hat by slot, for D reduce

  const int g = blockIdx.x & 3;        // c group (0..3)
  const int sg = blockIdx.x >> 2;      // spatial 0..287
  const int wave = threadIdx.x >> 6;   // 0..7
  const int lane = threadIdx.x & 63;
  const int c = g * 8 + wave;

  int t = sg;
  const int y = t % 6; t /= 6;
  const int xx = t % 6;
  const int n = t / 6;

  const float bvv = beta_v[0], bav = beta_a[0], lamv = lambda_[0];
  const float* wbase = Wt2 + (size_t)c * 4608;

  // ---- prefetch p_hat (global, coalesced) so vmcnt overlaps staging ----
  float phv[5];
  if (mode != 0) {
    const float* phb = p_hat + ((size_t)sg * 32 + c) * 288;
#pragma unroll
    for (int k = 0; k < 5; ++k) {
      int ch = lane + 64 * k; if (ch > 287) ch = 287;
      phv[k] = phb[ch];
    }
  }

  // ---- stage pose patch (coalesced float4), shared by all 8 waves ----
  for (int task = threadIdx.x; task < 1152; task += 512) {
    int ch = task >> 2, q = task & 3;
    int o = ch & 31, ij = ch >> 5;
    int i = ij / 3, j = ij - i * 3;
    int pix = (2 * xx + i) * 13 + (2 * y + j);
    v4f v = *(const v4f*)(posT +
        ((size_t)((n * 32 + o) * 169) + pix) * 16 + q * 4);
    *(v4f*)(sP + ch * 20 + q * 4) = v;
  }
  // ---- stage rhat scale: a/1152 or a/D (32-contiguous reads) ----
  for (int task = threadIdx.x; task < 288; task += 512) {
    int o = task & 31, ij = task >> 5;
    int i = ij / 3, j = ij - i * 3;
    int idx = ((size_t)n * 169 + (2 * xx + i) * 13 + (2 * y + j)) * 32 + o;
    float a = actT[idx];
    sE[task] = (mode == 0) ? a * (1.0f / 1152.0f) : a / Dread[idx];
  }
  __syncthreads();

  // ---- M step: software-pipelined (prefetch k+1 W/P/sE while computing k)
  float sum_r = 0.f;
  v2f sv2[8], sq2[8];
#pragma unroll
  for (int d = 0; d < 8; ++d) { sv2[d] = 0.f; sq2[d] = 0.f; }

  // prologue: k=0 (ch = lane < 64, always active)
  {
    const v4f* Pp = (const v4f*)(sP + lane * 20);
    const v4f* Wp = (const v4f*)(wbase + lane * 16);
    v4f P0 = Pp[0], P1 = Pp[1], P2 = Pp[2], P3 = Pp[3];
    v4f W0 = Wp[0], W1 = Wp[1], W2 = Wp[2], W3 = Wp[3];
    float en = sE[lane];

#pragma unroll
    for (int k = 0; k < 5; ++k) {
      v4f Pn0 = 0.f, Pn1 = 0.f, Pn2 = 0.f, Pn3 = 0.f;
      v4f Wn0 = 0.f, Wn1 = 0.f, Wn2 = 0.f, Wn3 = 0.f;
      float enn = 0.f;
      if (k < 4) {
        int chn = lane + 64 * (k + 1);
        int chnm = (chn < 288) ? chn : 0;
        const v4f* Pn = (const v4f*)(sP + chnm * 20);
        Pn0 = Pn[0]; Pn1 = Pn[1]; Pn2 = Pn[2]; Pn3 = Pn[3];
        const v4f* Wn = (const v4f*)(wbase + chnm * 16);
        Wn0 = Wn[0]; Wn1 = Wn[1]; Wn2 = Wn[2]; Wn3 = Wn[3];
        enn = sE[chnm];
      }

      int ch = lane + 64 * k;
      float rhat = en;
      if (mode != 0) rhat *= phv[k];
      if (ch >= 288) rhat = 0.f;
      sum_r += rhat;

      v2f PL0 = lo2(P0), PH0 = hi2(P0), PL1 = lo2(P1), PH1 = hi2(P1);
      v2f PL2 = lo2(P2), PH2 = hi2(P2), PL3 = lo2(P3), PH3 = hi2(P3);
      v2f r2 = rhat;

#pragma unroll
      for (int p = 0; p < 4; ++p) {
        v4f Wr = (p == 0) ? W0 : (p == 1) ? W1 : (p == 2) ? W2 : W3;
        v2f vlo = Wr.x * PL0 + Wr.y * PL1 + Wr.z * PL2 + Wr.w * PL3;
        v2f vhi = Wr.x * PH0 + Wr.y * PH1 + Wr.z * PH2 + Wr.w * PH3;
        v2f tlo = r2 * vlo, thi = r2 * vhi;
        sv2[p * 2 + 0] += tlo;
        sv2[p * 2 + 1] += thi;
        sq2[p * 2 + 0] += tlo * vlo;
        sq2[p * 2 + 1] += thi * vhi;
      }

      if (k < 4) {
        P0 = Pn0; P1 = Pn1; P2 = Pn2; P3 = Pn3;
        W0 = Wn0; W1 = Wn1; W2 = Wn2; W3 = Wn3;
        en = enn;
      }
    }
  }

  // ---- issue E-loop k=0 loads now; they complete under the ~600 reg-only
  //      cycles of DPP reductions below ----
  v4f EP0 = 0.f, EP1 = 0.f, EP2 = 0.f, EP3 = 0.f;
  v4f EW0 = 0.f, EW1 = 0.f, EW2 = 0.f, EW3 = 0.f;
  if (mode != 2) {
    const v4f* Pe = (const v4f*)(sP + lane * 20);
    EP0 = Pe[0]; EP1 = Pe[1]; EP2 = Pe[2]; EP3 = Pe[3];
    const v4f* We = (const v4f*)(wbase + lane * 16);
    EW0 = We[0]; EW1 = We[1]; EW2 = We[2]; EW3 = We[3];
  }

  sum_r = wsum64(sum_r);
  const float inv_sr = 1.0f / sum_r;
  float mu[16];
  float lsum = 0.f;
#pragma unroll
  for (int d = 0; d < 16; ++d) {
    float s1 = wsum64(sv2[d >> 1][d & 1]);
    float s2 = wsum64(sq2[d >> 1][d & 1]);
    float m = s1 * inv_sr;
    mu[d] = m;
    float sg_ = fmaxf(s2 * inv_sr - m * m, 1e-30f);
    lsum += __logf(sg_);
  }
  const float cost = (16.f * bvv + lsum) * sum_r;
  const float aout = 1.0f / (1.0f + __expf(-lamv * (bav - cost)));

  if (mode == 2) {
    if (lane == 0) {
      float* ob = out + (size_t)(n * 544 + c * 16) * 36 + xx * 6 + y;
#pragma unroll
      for (int d = 0; d < 16; ++d) ob[d * 36] = mu[d];
      out[(size_t)(n * 544 + 512 + c) * 36 + xx * 6 + y] = aout;
    }
    return;
  }

  // ---- E step: software-pipelined vote recompute, store to kperm'd slot --
  v2f mu2[8];
#pragma unroll
  for (int d = 0; d < 8; ++d) { mu2[d].x = mu[2 * d]; mu2[d].y = mu[2 * d + 1]; }
  const float G = __logf(aout) - 0.5f * (lsum + 16.f * 1.8378770664093453f);

#pragma unroll
  for (int k = 0; k < 5; ++k) {
    v4f Pn0 = 0.f, Pn1 = 0.f, Pn2 = 0.f, Pn3 = 0.f;
    v4f Wn0 = 0.f, Wn1 = 0.f, Wn2 = 0.f, Wn3 = 0.f;
    if (k < 4) {
      int chn = lane + 64 * (k + 1);
      int chnm = (chn < 288) ? chn : 0;
      const v4f* Pn = (const v4f*)(sP + chnm * 20);
      Pn0 = Pn[0]; Pn1 = Pn[1]; Pn2 = Pn[2]; Pn3 = Pn[3];
      const v4f* Wn = (const v4f*)(wbase + chnm * 16);
      Wn0 = Wn[0]; Wn1 = Wn[1]; Wn2 = Wn[2]; Wn3 = Wn[3];
    }

    // compute for all lanes (clamped lanes produce garbage, store guarded)
    v2f PL0 = lo2(EP0), PH0 = hi2(EP0), PL1 = lo2(EP1), PH1 = hi2(EP1);
    v2f PL2 = lo2(EP2), PH2 = hi2(EP2), PL3 = lo2(EP3), PH3 = hi2(EP3);
    v2f ss2 = 0.f;
#pragma unroll
    for (int p = 0; p < 4; ++p) {
      v4f Wr = (p == 0) ? EW0 : (p == 1) ? EW1 : (p == 2) ? EW2 : EW3;
      v2f vlo = Wr.x * PL0 + Wr.y * PL1 + Wr.z * PL2 + Wr.w * PL3;
      v2f vhi = Wr.x * PH0 + Wr.y * PH1 + Wr.z * PH2 + Wr.w * PH3;
      v2f dlo = vlo - mu2[p * 2 + 0];
      v2f dhi = vhi - mu2[p * 2 + 1];
      ss2 += dlo * dlo;
      ss2 += dhi * dhi;
    }
    float ss = ss2.x + ss2.y;
    float ph = __expf(G - ss);

    int mch = lane + 64 * k;
    if (mch < 288) {
      int o = mch & 31, ijm = mch >> 5;
      int im = ijm / 3, jm = ijm - im * 3;
      int i2 = (im == 0) ? 0 : 3 - im;   // kperm = {0,2,1}, involution
      int j2 = (jm == 0) ? 0 : 3 - jm;
      int slot = (i2 * 3 + j2) * 32 + o;
      p_hat[((size_t)sg * 32 + c) * 288 + slot] = ph;
      sPh[wave * 288 + slot] = ph;
    }

    if (k < 4) {
      EP0 = Pn0; EP1 = Pn1; EP2 = Pn2; EP3 = Pn3;
      EW0 = Wn0; EW1 = Wn1; EW2 = Wn2; EW3 = Wn3;
    }
  }
  __syncthreads();
  // D reduce over block's 8 c + global atomic (4 c-grp blocks contribute)
  for (int t2 = threadIdx.x; t2 < 288; t2 += 512) {
    float s = sPh[t2] + sPh[288 + t2] + sPh[576 + t2] + sPh[864 + t2]
            + sPh[1152 + t2] + sPh[1440 + t2] + sPh[1728 + t2] + sPh[2016 + t2];
    int o = t2 & 31, ij = t2 >> 5;
    int i = ij / 3, j = ij - i * 3;
    atomicAdd(Dwrite + ((size_t)n * 169 + (2 * xx + i) * 13 + (2 * y + j)) * 32 + o, s);
  }
}

extern "C" void kernel_launch(void* const* d_in, const int* in_sizes, int n_in,
                              void* d_out, int out_size, void* d_ws,
                              size_t ws_size, hipStream_t stream) {
  const float* x   = (const float*)d_in[0];
  const float* Wt  = (const float*)d_in[1];
  const float* bv  = (const float*)d_in[2];
  const float* ba  = (const float*)d_in[3];
  const float* lam = (const float*)d_in[4];
  float* out = (float*)d_out;
  float* ws = (float*)d_ws;

  float* p_hat = ws + OFF_PHAT;
  float* D0    = ws + OFF_D0;
  float* D1    = ws + OFF_D1;
  float* posT  = ws + OFF_POST;
  float* actT  = ws + OFF_ACTT;
  float* Wt2   = ws + OFF_WT2;

  (void)in_sizes; (void)n_in; (void)out_size; (void)ws_size;

  // fused prep: transposes + zero D0/D1 (D0,D1 contiguous in ws)
  prep_kernel<<<3787, 256, 0, stream>>>(x, Wt, posT, actT, Wt2, D0);

  // M0 + E1 -> p_hat, D0
  em_kernel<<<1152, 512, 0, stream>>>(Wt2, posT, actT, p_hat, D1, D0,
                                      bv, ba, lam, out, 0);
  // M1 (p_hat, D0) + E2 -> p_hat, D1
  em_kernel<<<1152, 512, 0, stream>>>(Wt2, posT, actT, p_hat, D0, D1,
                                      bv, ba, lam, out, 1);
  // M2 (p_hat, D1) -> out
  em_kernel<<<1152, 512, 0, stream>>>(Wt2, posT, actT, p_hat, D1, D0,
                                      bv, ba, lam, out, 2);
}

// Round 5
// 187.976 us; speedup vs baseline: 2.0593x; 2.0593x over previous
//
#include <hip/hip_runtime.h>

// ---------------------------------------------------------------------------
// ConvCaps (EM routing): b=8, B=32, C=32, K=3, stride=2, Win=13, Wout=6, 3 iters
// x: (8, 544, 13, 13) f32   [pose 512ch = (q,r,o), act 32ch]
// W: (3,3,32,32,4,4) f32    [ch=(ij*32+o)][c][p][q], 512 floats per ch
// out: (8, 544, 6, 6) f32
// vote[d=p*4+r] = sum_q W[ch][c][p][q] * pose[n,q,r,o, 2x+i, 2y+j]
//
// R15 = R14 pipeline (1-deep SW pipelining of M and E k-loops) with
// __launch_bounds__(512, 2).
// R14 post-mortem: VGPR_Count=64 + 361MB WRITE/em proves the 2nd
// launch-bounds arg acts as min WORKGROUPS/CU on this toolchain:
// (512,8)->cap32 (R12), (512,4)->cap64 (R14), (256,4)->cap64~ (R11 fit at
// 60). R14's pipeline needs ~110 VGPR -> spilled at cap 64; ILP hypothesis
// never tested. (512,2) -> 2 blocks/CU -> cap 128; LDS 2x33.8KB fits.
// R13 proved 20 vs 32 waves/CU neutral -> trading occupancy for ILP is the
// right experiment.
// Session rules: launch-bounds arg2 = blocks/CU here; VGPR cap = 
// 2048 / (arg2 * waves_per_block / 4SIMD... empirically 256/arg2 for
// 512-thr blocks). Spill symptom: WRITE_SIZE explodes 20x (R12/R14).
// p_hat slices are block-private; only D crosses blocks -> ping-pong D0/D1.
// ---------------------------------------------------------------------------

typedef float v2f __attribute__((ext_vector_type(2)));
typedef float v4f __attribute__((ext_vector_type(4)));

// workspace layout (floats)
#define OFF_PHAT 0           // 288*32*288 = 2654208   [spatial][c][slot]
#define OFF_D0   2654208     // 43264 = 8*169*32   [n][pix][o]
#define OFF_D1   2697472     // 43264
#define OFF_POST 2740736     // 692224 = 8*32*169*16   [(n,o)][pix][d]
#define OFF_ACTT 3432960     // 43264  [n][pix][o]
#define OFF_WT2  3476224     // 147456 = 32*288*16  [c][ch][d]
// total 3623680 floats = 14.5 MB

// DPP butterfly-reduce on the VALU pipe (no DS-pipe traffic).
template <int CTRL>
__device__ __forceinline__ float dppadd(float v) {
  int p = __builtin_amdgcn_update_dpp(0, __float_as_int(v), CTRL, 0xF, 0xF, true);
  return v + __int_as_float(p);
}

__device__ __forceinline__ float wsum64(float v) {
  v = dppadd<0xB1>(v);    // quad_perm {1,0,3,2}  : xor 1
  v = dppadd<0x4E>(v);    // quad_perm {2,3,0,1}  : xor 2
  v = dppadd<0x141>(v);   // row_half_mirror      : xor 7  -> 8-lane sums
  v = dppadd<0x140>(v);   // row_mirror           : xor 15 -> row (16) sums
  v = dppadd<0x142>(v);   // row_bcast15: row1 += row0, row3 += row2
  v = dppadd<0x143>(v);   // row_bcast31: rows 2,3 += (row0+row1); lane63 = total
  return __int_as_float(__builtin_amdgcn_readlane(__float_as_int(v), 63));
}

__device__ __forceinline__ v2f lo2(v4f a) { return __builtin_shufflevector(a, a, 0, 1); }
__device__ __forceinline__ v2f hi2(v4f a) { return __builtin_shufflevector(a, a, 2, 3); }

// One fused prep kernel (range-branched elementwise):
//   [0,692224)        pose transpose -> posT[((n*32+o)*169+pix)*16 + d]
//   [692224,735488)   act transpose  -> actT[n][pix][o]
//   [735488,882944)   W transpose    -> Wt2[c][ch][d]
//   [882944,969472)   zero D0 and D1
__global__ __launch_bounds__(256) void prep_kernel(
    const float* __restrict__ x, const float* __restrict__ Wt,
    float* __restrict__ posT, float* __restrict__ actT,
    float* __restrict__ Wt2, float* __restrict__ Dz) {
  int tid = blockIdx.x * 256 + threadIdx.x;   // 969472 = 3787*256
  if (tid < 692224) {
    int pix = tid % 169; int t = tid / 169;
    int o = t & 31; t >>= 5;
    int d = t & 15; int n = t >> 4;
    float v = x[((size_t)n * 544 + d * 32 + o) * 169 + pix];
    posT[((size_t)(n * 32 + o) * 169 + pix) * 16 + d] = v;
  } else if (tid < 735488) {
    int r = tid - 692224;
    int pix = r % 169; int t = r / 169;
    int o = t & 31; int n = t >> 5;
    float v = x[(size_t)n * 91936 + 86528 + o * 169 + pix];
    actT[((size_t)n * 169 + pix) * 32 + o] = v;
  } else if (tid < 882944) {
    int r = tid - 735488;                     // 147456 = 32*288*16
    int c = r / 4608; int s = r - c * 4608;
    int ch = s >> 4, d = s & 15;
    Wt2[r] = Wt[(size_t)ch * 512 + c * 16 + d];
  } else {
    Dz[tid - 882944] = 0.f;                   // D0 then D1 (contiguous)
  }
}

// Fused EM step. 512 threads = 8 waves, one c per wave (8 c's per block).
// mode 0: M(uniform Rp) + E -> p_hat, Dwrite
// mode 1: M(p_hat, Dread) + E -> p_hat, Dwrite
// mode 2: M(p_hat, Dread) -> final output
__global__ __launch_bounds__(512, 2) void em_kernel(
    const float* __restrict__ Wt2, const float* __restrict__ posT,
    const float* __restrict__ actT, float* __restrict__ p_hat,
    const float* __restrict__ Dread, float* __restrict__ Dwrite,
    const float* __restrict__ beta_v, const float* __restrict__ beta_a,
    const float* __restrict__ lambda_, float* __restrict__ out, int mode) {
  __shared__ float sP[288 * 20];   // pose patch, stride 20 (float4-aligned)
  __shared__ float sE[288];        // a/1152 or a/D per child slot
  __shared__ float sPh[8 * 288];   // per-wave p_hat by slot, for D reduce

  const int g = blockIdx.x & 3;        // c group (0..3)
  const int sg = blockIdx.x >> 2;      // spatial 0..287
  const int wave = threadIdx.x >> 6;   // 0..7
  const int lane = threadIdx.x & 63;
  const int c = g * 8 + wave;

  int t = sg;
  const int y = t % 6; t /= 6;
  const int xx = t % 6;
  const int n = t / 6;

  const float bvv = beta_v[0], bav = beta_a[0], lamv = lambda_[0];
  const float* wbase = Wt2 + (size_t)c * 4608;

  // ---- prefetch p_hat (global, coalesced) so vmcnt overlaps staging ----
  float phv[5];
  if (mode != 0) {
    const float* phb = p_hat + ((size_t)sg * 32 + c) * 288;
#pragma unroll
    for (int k = 0; k < 5; ++k) {
      int ch = lane + 64 * k; if (ch > 287) ch = 287;
      phv[k] = phb[ch];
    }
  }

  // ---- stage pose patch (coalesced float4), shared by all 8 waves ----
  for (int task = threadIdx.x; task < 1152; task += 512) {
    int ch = task >> 2, q = task & 3;
    int o = ch & 31, ij = ch >> 5;
    int i = ij / 3, j = ij - i * 3;
    int pix = (2 * xx + i) * 13 + (2 * y + j);
    v4f v = *(const v4f*)(posT +
        ((size_t)((n * 32 + o) * 169) + pix) * 16 + q * 4);
    *(v4f*)(sP + ch * 20 + q * 4) = v;
  }
  // ---- stage rhat scale: a/1152 or a/D (32-contiguous reads) ----
  for (int task = threadIdx.x; task < 288; task += 512) {
    int o = task & 31, ij = task >> 5;
    int i = ij / 3, j = ij - i * 3;
    int idx = ((size_t)n * 169 + (2 * xx + i) * 13 + (2 * y + j)) * 32 + o;
    float a = actT[idx];
    sE[task] = (mode == 0) ? a * (1.0f / 1152.0f) : a / Dread[idx];
  }
  __syncthreads();

  // ---- M step: software-pipelined (prefetch k+1 W/P/sE while computing k)
  float sum_r = 0.f;
  v2f sv2[8], sq2[8];
#pragma unroll
  for (int d = 0; d < 8; ++d) { sv2[d] = 0.f; sq2[d] = 0.f; }

  // prologue: k=0 (ch = lane < 64, always active)
  {
    const v4f* Pp = (const v4f*)(sP + lane * 20);
    const v4f* Wp = (const v4f*)(wbase + lane * 16);
    v4f P0 = Pp[0], P1 = Pp[1], P2 = Pp[2], P3 = Pp[3];
    v4f W0 = Wp[0], W1 = Wp[1], W2 = Wp[2], W3 = Wp[3];
    float en = sE[lane];

#pragma unroll
    for (int k = 0; k < 5; ++k) {
      v4f Pn0 = 0.f, Pn1 = 0.f, Pn2 = 0.f, Pn3 = 0.f;
      v4f Wn0 = 0.f, Wn1 = 0.f, Wn2 = 0.f, Wn3 = 0.f;
      float enn = 0.f;
      if (k < 4) {
        int chn = lane + 64 * (k + 1);
        int chnm = (chn < 288) ? chn : 0;
        const v4f* Pn = (const v4f*)(sP + chnm * 20);
        Pn0 = Pn[0]; Pn1 = Pn[1]; Pn2 = Pn[2]; Pn3 = Pn[3];
        const v4f* Wn = (const v4f*)(wbase + chnm * 16);
        Wn0 = Wn[0]; Wn1 = Wn[1]; Wn2 = Wn[2]; Wn3 = Wn[3];
        enn = sE[chnm];
      }

      int ch = lane + 64 * k;
      float rhat = en;
      if (mode != 0) rhat *= phv[k];
      if (ch >= 288) rhat = 0.f;
      sum_r += rhat;

      v2f PL0 = lo2(P0), PH0 = hi2(P0), PL1 = lo2(P1), PH1 = hi2(P1);
      v2f PL2 = lo2(P2), PH2 = hi2(P2), PL3 = lo2(P3), PH3 = hi2(P3);
      v2f r2 = rhat;

#pragma unroll
      for (int p = 0; p < 4; ++p) {
        v4f Wr = (p == 0) ? W0 : (p == 1) ? W1 : (p == 2) ? W2 : W3;
        v2f vlo = Wr.x * PL0 + Wr.y * PL1 + Wr.z * PL2 + Wr.w * PL3;
        v2f vhi = Wr.x * PH0 + Wr.y * PH1 + Wr.z * PH2 + Wr.w * PH3;
        v2f tlo = r2 * vlo, thi = r2 * vhi;
        sv2[p * 2 + 0] += tlo;
        sv2[p * 2 + 1] += thi;
        sq2[p * 2 + 0] += tlo * vlo;
        sq2[p * 2 + 1] += thi * vhi;
      }

      if (k < 4) {
        P0 = Pn0; P1 = Pn1; P2 = Pn2; P3 = Pn3;
        W0 = Wn0; W1 = Wn1; W2 = Wn2; W3 = Wn3;
        en = enn;
      }
    }
  }

  // ---- issue E-loop k=0 loads now; they complete under the ~600 reg-only
  //      cycles of DPP reductions below ----
  v4f EP0 = 0.f, EP1 = 0.f, EP2 = 0.f, EP3 = 0.f;
  v4f EW0 = 0.f, EW1 = 0.f, EW2 = 0.f, EW3 = 0.f;
  if (mode != 2) {
    const v4f* Pe = (const v4f*)(sP + lane * 20);
    EP0 = Pe[0]; EP1 = Pe[1]; EP2 = Pe[2]; EP3 = Pe[3];
    const v4f* We = (const v4f*)(wbase + lane * 16);
    EW0 = We[0]; EW1 = We[1]; EW2 = We[2]; EW3 = We[3];
  }

  sum_r = wsum64(sum_r);
  const float inv_sr = 1.0f / sum_r;
  float mu[16];
  float lsum = 0.f;
#pragma unroll
  for (int d = 0; d < 16; ++d) {
    float s1 = wsum64(sv2[d >> 1][d & 1]);
    float s2 = wsum64(sq2[d >> 1][d & 1]);
    float m = s1 * inv_sr;
    mu[d] = m;
    float sg_ = fmaxf(s2 * inv_sr - m * m, 1e-30f);
    lsum += __logf(sg_);
  }
  const float cost = (16.f * bvv + lsum) * sum_r;
  const float aout = 1.0f / (1.0f + __expf(-lamv * (bav - cost)));

  if (mode == 2) {
    if (lane == 0) {
      float* ob = out + (size_t)(n * 544 + c * 16) * 36 + xx * 6 + y;
#pragma unroll
      for (int d = 0; d < 16; ++d) ob[d * 36] = mu[d];
      out[(size_t)(n * 544 + 512 + c) * 36 + xx * 6 + y] = aout;
    }
    return;
  }

  // ---- E step: software-pipelined vote recompute, store to kperm'd slot --
  v2f mu2[8];
#pragma unroll
  for (int d = 0; d < 8; ++d) { mu2[d].x = mu[2 * d]; mu2[d].y = mu[2 * d + 1]; }
  const float G = __logf(aout) - 0.5f * (lsum + 16.f * 1.8378770664093453f);

#pragma unroll
  for (int k = 0; k < 5; ++k) {
    v4f Pn0 = 0.f, Pn1 = 0.f, Pn2 = 0.f, Pn3 = 0.f;
    v4f Wn0 = 0.f, Wn1 = 0.f, Wn2 = 0.f, Wn3 = 0.f;
    if (k < 4) {
      int chn = lane + 64 * (k + 1);
      int chnm = (chn < 288) ? chn : 0;
      const v4f* Pn = (const v4f*)(sP + chnm * 20);
      Pn0 = Pn[0]; Pn1 = Pn[1]; Pn2 = Pn[2]; Pn3 = Pn[3];
      const v4f* Wn = (const v4f*)(wbase + chnm * 16);
      Wn0 = Wn[0]; Wn1 = Wn[1]; Wn2 = Wn[2]; Wn3 = Wn[3];
    }

    // compute for all lanes (clamped lanes produce garbage, store guarded)
    v2f PL0 = lo2(EP0), PH0 = hi2(EP0), PL1 = lo2(EP1), PH1 = hi2(EP1);
    v2f PL2 = lo2(EP2), PH2 = hi2(EP2), PL3 = lo2(EP3), PH3 = hi2(EP3);
    v2f ss2 = 0.f;
#pragma unroll
    for (int p = 0; p < 4; ++p) {
      v4f Wr = (p == 0) ? EW0 : (p == 1) ? EW1 : (p == 2) ? EW2 : EW3;
      v2f vlo = Wr.x * PL0 + Wr.y * PL1 + Wr.z * PL2 + Wr.w * PL3;
      v2f vhi = Wr.x * PH0 + Wr.y * PH1 + Wr.z * PH2 + Wr.w * PH3;
      v2f dlo = vlo - mu2[p * 2 + 0];
      v2f dhi = vhi - mu2[p * 2 + 1];
      ss2 += dlo * dlo;
      ss2 += dhi * dhi;
    }
    float ss = ss2.x + ss2.y;
    float ph = __expf(G - ss);

    int mch = lane + 64 * k;
    if (mch < 288) {
      int o = mch & 31, ijm = mch >> 5;
      int im = ijm / 3, jm = ijm - im * 3;
      int i2 = (im == 0) ? 0 : 3 - im;   // kperm = {0,2,1}, involution
      int j2 = (jm == 0) ? 0 : 3 - jm;
      int slot = (i2 * 3 + j2) * 32 + o;
      p_hat[((size_t)sg * 32 + c) * 288 + slot] = ph;
      sPh[wave * 288 + slot] = ph;
    }

    if (k < 4) {
      EP0 = Pn0; EP1 = Pn1; EP2 = Pn2; EP3 = Pn3;
      EW0 = Wn0; EW1 = Wn1; EW2 = Wn2; EW3 = Wn3;
    }
  }
  __syncthreads();
  // D reduce over block's 8 c + global atomic (4 c-grp blocks contribute)
  for (int t2 = threadIdx.x; t2 < 288; t2 += 512) {
    float s = sPh[t2] + sPh[288 + t2] + sPh[576 + t2] + sPh[864 + t2]
            + sPh[1152 + t2] + sPh[1440 + t2] + sPh[1728 + t2] + sPh[2016 + t2];
    int o = t2 & 31, ij = t2 >> 5;
    int i = ij / 3, j = ij - i * 3;
    atomicAdd(Dwrite + ((size_t)n * 169 + (2 * xx + i) * 13 + (2 * y + j)) * 32 + o, s);
  }
}

extern "C" void kernel_launch(void* const* d_in, const int* in_sizes, int n_in,
                              void* d_out, int out_size, void* d_ws,
                              size_t ws_size, hipStream_t stream) {
  const float* x   = (const float*)d_in[0];
  const float* Wt  = (const float*)d_in[1];
  const float* bv  = (const float*)d_in[2];
  const float* ba  = (const float*)d_in[3];
  const float* lam = (const float*)d_in[4];
  float* out = (float*)d_out;
  float* ws = (float*)d_ws;

  float* p_hat = ws + OFF_PHAT;
  float* D0    = ws + OFF_D0;
  float* D1    = ws + OFF_D1;
  float* posT  = ws + OFF_POST;
  float* actT  = ws + OFF_ACTT;
  float* Wt2   = ws + OFF_WT2;

  (void)in_sizes; (void)n_in; (void)out_size; (void)ws_size;

  // fused prep: transposes + zero D0/D1 (D0,D1 contiguous in ws)
  prep_kernel<<<3787, 256, 0, stream>>>(x, Wt, posT, actT, Wt2, D0);

  // M0 + E1 -> p_hat, D0
  em_kernel<<<1152, 512, 0, stream>>>(Wt2, posT, actT, p_hat, D1, D0,
                                      bv, ba, lam, out, 0);
  // M1 (p_hat, D0) + E2 -> p_hat, D1
  em_kernel<<<1152, 512, 0, stream>>>(Wt2, posT, actT, p_hat, D0, D1,
                                      bv, ba, lam, out, 1);
  // M2 (p_hat, D1) -> out
  em_kernel<<<1152, 512, 0, stream>>>(Wt2, posT, actT, p_hat, D1, D0,
                                      bv, ba, lam, out, 2);
}

// Round 9
// 172.850 us; speedup vs baseline: 2.2395x; 1.0875x over previous
//
#include <hip/hip_runtime.h>

// ---------------------------------------------------------------------------
// ConvCaps (EM routing): b=8, B=32, C=32, K=3, stride=2, Win=13, Wout=6, 3 iters
// x: (8, 544, 13, 13) f32   [pose 512ch = (q,r,o), act 32ch]
// W: (3,3,32,32,4,4) f32    [ch=(ij*32+o)][c][p][q], 512 floats per ch
// out: (8, 544, 6, 6) f32
// vote[d=p*4+r] = sum_q W[ch][c][p][q] * pose[n,q,r,o, 2x+i, 2y+j]
//
// R19 = R11 structure (3-launch, 256thr/4-wave, grid 2304, DPP reductions)
// with the LDS pose-staging round-trip ELIMINATED:
//  - prep materializes patch-major posP[sg][ch][16] (5.3MB, L2-resident);
//    em reads P fragments DIRECTLY from global (per-lane contiguous v4f x4).
//    Deletes sP (23KB LDS), its stage loop, and its barrier. LDS -> 5.8KB.
//  - mode is a template param (3 specialized kernels).
//  - 16 __logf -> 4 via 4-sigma products (tolerance 0.02 >> 2.4e-4 current).
// Rationale: R15 counters showed avg occupancy 5.6 waves/CU vs 16 resident
// -> waves stalled ~93% of life; the untested chain was the staging
// global->LDS->barrier->VGPR round-trip on L2-resident data (learn_hip
// common-mistake #7; dropping V-staging was +26% there).
// Session rules: spin barriers + cooperative launch: BANNED (R16-R18 = 3
// dead benches). launch-bounds arg2 = blocks/CU; (256,2) -> cap ~256 =
// spill-impossible. Spill symptom: WRITE_SIZE x20 (R12/R14). TLP neutral
// (R13), explicit ILP neutral (R15), DPP reduction +8% (R11).
// p_hat slices are block-private; only D crosses blocks -> ping-pong D0/D1.
// ---------------------------------------------------------------------------

typedef float v2f __attribute__((ext_vector_type(2)));
typedef float v4f __attribute__((ext_vector_type(4)));

// workspace layout (floats)
#define OFF_PHAT 0           // 288*32*288 = 2654208   [spatial][c][slot]
#define OFF_D0   2654208     // 43264 = 8*169*32   [n][pix][o]
#define OFF_D1   2697472     // 43264
#define OFF_POSP 2740736     // 1327104 = 288*288*16  [sg][ch][d] patch-major
#define OFF_ACTT 4067840     // 43264  [n][pix][o]
#define OFF_WT2  4111104     // 147456 = 32*288*16  [c][ch][d]
// total 4258560 floats = 17.0 MB (ws is 256MB)

// DPP butterfly-reduce on the VALU pipe (no DS-pipe traffic).
template <int CTRL>
__device__ __forceinline__ float dppadd(float v) {
  int p = __builtin_amdgcn_update_dpp(0, __float_as_int(v), CTRL, 0xF, 0xF, true);
  return v + __int_as_float(p);
}

__device__ __forceinline__ float wsum64(float v) {
  v = dppadd<0xB1>(v);    // quad_perm {1,0,3,2}  : xor 1
  v = dppadd<0x4E>(v);    // quad_perm {2,3,0,1}  : xor 2
  v = dppadd<0x141>(v);   // row_half_mirror      : xor 7  -> 8-lane sums
  v = dppadd<0x140>(v);   // row_mirror           : xor 15 -> row (16) sums
  v = dppadd<0x142>(v);   // row_bcast15: row1 += row0, row3 += row2
  v = dppadd<0x143>(v);   // row_bcast31: rows 2,3 += (row0+row1); lane63 = total
  return __int_as_float(__builtin_amdgcn_readlane(__float_as_int(v), 63));
}

__device__ __forceinline__ v2f lo2(v4f a) { return __builtin_shufflevector(a, a, 0, 1); }
__device__ __forceinline__ v2f hi2(v4f a) { return __builtin_shufflevector(a, a, 2, 3); }

// One fused prep kernel (range-branched elementwise), 6267*256 = 1604352:
//   [0,1327104)          patch-major pose: posP[(sg*288+ch)*16+d] from x
//   [1327104,1370368)    act transpose  -> actT[n][pix][o]
//   [1370368,1517824)    W transpose    -> Wt2[c][ch][d]
//   [1517824,1604352)    zero D0 and D1
__global__ __launch_bounds__(256) void prep_kernel(
    const float* __restrict__ x, const float* __restrict__ Wt,
    float* __restrict__ posP, float* __restrict__ actT,
    float* __restrict__ Wt2, float* __restrict__ Dz) {
  int tid = blockIdx.x * 256 + threadIdx.x;
  if (tid < 1327104) {
    int d = tid & 15; int t = tid >> 4;      // t = sg*288 + ch
    int ch = t % 288; int sg = t / 288;
    int o = ch & 31, ij = ch >> 5;
    int i = ij / 3, j = ij - i * 3;
    int y = sg % 6; int t2 = sg / 6;
    int xx = t2 % 6; int n = t2 / 6;
    int pix = (2 * xx + i) * 13 + (2 * y + j);
    posP[tid] = x[((size_t)n * 544 + d * 32 + o) * 169 + pix];
  } else if (tid < 1370368) {
    int r = tid - 1327104;
    int pix = r % 169; int t = r / 169;
    int o = t & 31; int n = t >> 5;
    float v = x[(size_t)n * 91936 + 86528 + o * 169 + pix];
    actT[((size_t)n * 169 + pix) * 32 + o] = v;
  } else if (tid < 1517824) {
    int r = tid - 1370368;                    // 147456 = 32*288*16
    int c = r / 4608; int s = r - c * 4608;
    int ch = s >> 4, d = s & 15;
    Wt2[r] = Wt[(size_t)ch * 512 + c * 16 + d];
  } else {
    Dz[tid - 1517824] = 0.f;                  // D0 then D1 (contiguous)
  }
}

// Fused EM step, mode as template (DCE per phase).
// MODE 0: M(uniform Rp) + E -> p_hat, Dwrite
// MODE 1: M(p_hat, Dread) + E -> p_hat, Dwrite
// MODE 2: M(p_hat, Dread) -> final output
template <int MODE>
__global__ __launch_bounds__(256, 2) void em_kernel(
    const float* __restrict__ Wt2, const float* __restrict__ posP,
    const float* __restrict__ actT, float* __restrict__ p_hat,
    const float* __restrict__ Dread, float* __restrict__ Dwrite,
    const float* __restrict__ beta_v, const float* __restrict__ beta_a,
    const float* __restrict__ lambda_, float* __restrict__ out) {
  __shared__ float sE[288];        // a/1152 or a/D per child slot
  __shared__ float sPh[4 * 288];   // per-wave p_hat by slot, for D reduce

  const int g = blockIdx.x & 7;        // c group
  const int sg = blockIdx.x >> 3;      // spatial 0..287
  const int wave = threadIdx.x >> 6;
  const int lane = threadIdx.x & 63;
  const int c = g * 4 + wave;

  int t = sg;
  const int y = t % 6; t /= 6;
  const int xx = t % 6;
  const int n = t / 6;

  const float bvv = beta_v[0], bav = beta_a[0], lamv = lambda_[0];
  const float* wbase = Wt2 + (size_t)c * 4608;
  const float* pbase = posP + (size_t)sg * 288 * 16;

  // ---- prefetch p_hat (global, coalesced) ----
  float phv[5];
  if (MODE != 0) {
    const float* phb = p_hat + ((size_t)sg * 32 + c) * 288;
#pragma unroll
    for (int k = 0; k < 5; ++k) {
      int ch = lane + 64 * k; if (ch > 287) ch = 287;
      phv[k] = phb[ch];
    }
  }

  // ---- stage rhat scale: a/1152 or a/D (32-contiguous reads) ----
  for (int task = threadIdx.x; task < 288; task += 256) {
    int o = task & 31, ij = task >> 5;
    int i = ij / 3, j = ij - i * 3;
    int idx = ((size_t)n * 169 + (2 * xx + i) * 13 + (2 * y + j)) * 32 + o;
    float a = actT[idx];
    sE[task] = (MODE == 0) ? a * (1.0f / 1152.0f) : a / Dread[idx];
  }
  __syncthreads();

  // ---- M step: packed float2 accumulation; P direct from global/L2 ----
  float sum_r = 0.f;
  v2f sv2[8], sq2[8];
#pragma unroll
  for (int d = 0; d < 8; ++d) { sv2[d] = 0.f; sq2[d] = 0.f; }

#pragma unroll
  for (int k = 0; k < 5; ++k) {
    int ch = lane + 64 * k;
    const bool act_l = (ch < 288);
    const int chm = act_l ? ch : 0;

    const v4f* Pp = (const v4f*)(pbase + (size_t)chm * 16);
    v4f P0 = Pp[0], P1 = Pp[1], P2 = Pp[2], P3 = Pp[3];
    const v4f* Wp = (const v4f*)(wbase + chm * 16);
    v4f W0 = Wp[0], W1 = Wp[1], W2 = Wp[2], W3 = Wp[3];

    float rhat = sE[chm];
    if (MODE != 0) rhat *= phv[k];
    if (!act_l) rhat = 0.f;
    sum_r += rhat;

    v2f PL0 = lo2(P0), PH0 = hi2(P0), PL1 = lo2(P1), PH1 = hi2(P1);
    v2f PL2 = lo2(P2), PH2 = hi2(P2), PL3 = lo2(P3), PH3 = hi2(P3);
    v2f r2 = rhat;

#pragma unroll
    for (int p = 0; p < 4; ++p) {
      v4f Wr = (p == 0) ? W0 : (p == 1) ? W1 : (p == 2) ? W2 : W3;
      v2f vlo = Wr.x * PL0 + Wr.y * PL1 + Wr.z * PL2 + Wr.w * PL3;
      v2f vhi = Wr.x * PH0 + Wr.y * PH1 + Wr.z * PH2 + Wr.w * PH3;
      v2f tlo = r2 * vlo, thi = r2 * vhi;
      sv2[p * 2 + 0] += tlo;
      sv2[p * 2 + 1] += thi;
      sq2[p * 2 + 0] += tlo * vlo;
      sq2[p * 2 + 1] += thi * vhi;
    }
  }

  sum_r = wsum64(sum_r);
  const float inv_sr = 1.0f / sum_r;
  float mu[16];
  float lsum = 0.f;
  float prod = 1.f;
#pragma unroll
  for (int d = 0; d < 16; ++d) {
    float s1 = wsum64(sv2[d >> 1][d & 1]);
    float s2 = wsum64(sq2[d >> 1][d & 1]);
    float m = s1 * inv_sr;
    mu[d] = m;
    float sg_ = fmaxf(s2 * inv_sr - m * m, 1e-30f);
    prod *= sg_;
    if ((d & 3) == 3) { lsum += __logf(prod); prod = 1.f; }
  }
  const float cost = (16.f * bvv + lsum) * sum_r;
  const float aout = 1.0f / (1.0f + __expf(-lamv * (bav - cost)));

  if (MODE == 2) {
    if (lane == 0) {
      float* ob = out + (size_t)(n * 544 + c * 16) * 36 + xx * 6 + y;
#pragma unroll
      for (int d = 0; d < 16; ++d) ob[d * 36] = mu[d];
      out[(size_t)(n * 544 + 512 + c) * 36 + xx * 6 + y] = aout;
    }
    return;
  }

  // ---- E step: recompute votes (P direct), store to kperm'd slot ----
  v2f mu2[8];
#pragma unroll
  for (int d = 0; d < 8; ++d) { mu2[d].x = mu[2 * d]; mu2[d].y = mu[2 * d + 1]; }
  const float G = __logf(aout) - 0.5f * (lsum + 16.f * 1.8378770664093453f);

#pragma unroll
  for (int k = 0; k < 5; ++k) {
    int mch = lane + 64 * k;
    if (mch < 288) {
      const v4f* Pp = (const v4f*)(pbase + (size_t)mch * 16);
      v4f P0 = Pp[0], P1 = Pp[1], P2 = Pp[2], P3 = Pp[3];
      const v4f* Wp = (const v4f*)(wbase + mch * 16);
      v4f W0 = Wp[0], W1 = Wp[1], W2 = Wp[2], W3 = Wp[3];

      v2f PL0 = lo2(P0), PH0 = hi2(P0), PL1 = lo2(P1), PH1 = hi2(P1);
      v2f PL2 = lo2(P2), PH2 = hi2(P2), PL3 = lo2(P3), PH3 = hi2(P3);
      v2f ss2 = 0.f;
#pragma unroll
      for (int p = 0; p < 4; ++p) {
        v4f Wr = (p == 0) ? W0 : (p == 1) ? W1 : (p == 2) ? W2 : W3;
        v2f vlo = Wr.x * PL0 + Wr.y * PL1 + Wr.z * PL2 + Wr.w * PL3;
        v2f vhi = Wr.x * PH0 + Wr.y * PH1 + Wr.z * PH2 + Wr.w * PH3;
        v2f dlo = vlo - mu2[p * 2 + 0];
        v2f dhi = vhi - mu2[p * 2 + 1];
        ss2 += dlo * dlo;
        ss2 += dhi * dhi;
      }
      float ss = ss2.x + ss2.y;
      float ph = __expf(G - ss);
      int o = mch & 31, ijm = mch >> 5;
      int im = ijm / 3, jm = ijm - im * 3;
      int i2 = (im == 0) ? 0 : 3 - im;   // kperm = {0,2,1}, involution
      int j2 = (jm == 0) ? 0 : 3 - jm;
      int slot = (i2 * 3 + j2) * 32 + o;
      p_hat[((size_t)sg * 32 + c) * 288 + slot] = ph;
      sPh[wave * 288 + slot] = ph;
    }
  }
  __syncthreads();
  // D reduce over block's 4 c + global atomic (8 c-grp blocks contribute)
  for (int t2 = threadIdx.x; t2 < 288; t2 += 256) {
    float s = sPh[t2] + sPh[288 + t2] + sPh[576 + t2] + sPh[864 + t2];
    int o = t2 & 31, ij = t2 >> 5;
    int i = ij / 3, j = ij - i * 3;
    atomicAdd(Dwrite + ((size_t)n * 169 + (2 * xx + i) * 13 + (2 * y + j)) * 32 + o, s);
  }
}

extern "C" void kernel_launch(void* const* d_in, const int* in_sizes, int n_in,
                              void* d_out, int out_size, void* d_ws,
                              size_t ws_size, hipStream_t stream) {
  const float* x   = (const float*)d_in[0];
  const float* Wt  = (const float*)d_in[1];
  const float* bv  = (const float*)d_in[2];
  const float* ba  = (const float*)d_in[3];
  const float* lam = (const float*)d_in[4];
  float* out = (float*)d_out;
  float* ws = (float*)d_ws;

  float* p_hat = ws + OFF_PHAT;
  float* D0    = ws + OFF_D0;
  float* D1    = ws + OFF_D1;
  float* posP  = ws + OFF_POSP;
  float* actT  = ws + OFF_ACTT;
  float* Wt2   = ws + OFF_WT2;

  (void)in_sizes; (void)n_in; (void)out_size; (void)ws_size;

  // fused prep: patch-major pose + transposes + zero D0/D1
  prep_kernel<<<6267, 256, 0, stream>>>(x, Wt, posP, actT, Wt2, D0);

  // M0 + E1 -> p_hat, D0
  em_kernel<0><<<2304, 256, 0, stream>>>(Wt2, posP, actT, p_hat, D1, D0,
                                         bv, ba, lam, out);
  // M1 (p_hat, D0) + E2 -> p_hat, D1
  em_kernel<1><<<2304, 256, 0, stream>>>(Wt2, posP, actT, p_hat, D0, D1,
                                         bv, ba, lam, out);
  // M2 (p_hat, D1) -> out
  em_kernel<2><<<2304, 256, 0, stream>>>(Wt2, posP, actT, p_hat, D1, D0,
                                         bv, ba, lam, out);
}

// Round 10
// 143.224 us; speedup vs baseline: 2.7027x; 1.2069x over previous
//
#include <hip/hip_runtime.h>

// ---------------------------------------------------------------------------
// ConvCaps (EM routing): b=8, B=32, C=32, K=3, stride=2, Win=13, Wout=6, 3 iters
// x: (8, 544, 13, 13) f32   [pose 512ch = (q,r,o), act 32ch]
// W: (3,3,32,32,4,4) f32    [ch=(ij*32+o)][c][p][q], 512 floats per ch
// out: (8, 544, 6, 6) f32
// vote[d=p*4+r] = sum_q W[ch][c][p][q] * pose[n,q,r,o, 2x+i, 2y+j]
//
// R20 = R11 structure (best passing: 3-launch, 256thr/4-wave, grid 2304, sP
// LDS staging, DPP reductions) + TA-COALESCED W LAYOUT:
//   Wt3[((c*5+k)*4+q)*256 + lane*4 + j] = W[ch=64k+lane][c][d=4q+j] (0-pad
//   ch>=288). A W-load instruction now reads lane-contiguous 1KB (16 cache
//   lines) instead of 64B-strided (64 lines) -> 4x less TA address work on
//   the dominant load stream (40 W-loads/wave).
// Theory: per-em pinned ~43us, occupancy-neutral (R13), prefetch-NEGATIVE
// (R15), VALU 15% / HBM 8% / LDS ~0 -> bound by per-CU TA line-request
// throughput: 40 instr x 64 lines x 36 waves/CU ~ 92K line-ops ~ 38us @
// 1/cyc == the measured time. R19 (P scattered from global too) regressed,
// consistent. Also kept from R19: template MODE, 4-log product. Reverted:
// posP direct-global P reads (back to sP staging), scattered posP prep.
// Session rules: spin barriers + coop launch BANNED (R16-18). launch-bounds
// arg2 = blocks/CU, cap=256/arg2@512thr, 128@(256,2) = spill-impossible.
// Spill symptom: WRITE_SIZE x20. TLP neutral (R13), ILP neutral (R15), DPP
// +8% (R11). p_hat block-private; only D crosses blocks -> ping-pong D0/D1.
// ---------------------------------------------------------------------------

typedef float v2f __attribute__((ext_vector_type(2)));
typedef float v4f __attribute__((ext_vector_type(4)));

// workspace layout (floats)
#define OFF_PHAT 0           // 288*32*288 = 2654208   [spatial][c][slot]
#define OFF_D0   2654208     // 43264 = 8*169*32   [n][pix][o]
#define OFF_D1   2697472     // 43264
#define OFF_POST 2740736     // 692224 = 8*32*169*16   [(n,o)][pix][d]
#define OFF_ACTT 3432960     // 43264  [n][pix][o]
#define OFF_WT3  3476224     // 163840 = 32*5*4*256  [c][k][q][lane][4]
// total 3640064 floats = 14.6 MB

// DPP butterfly-reduce on the VALU pipe (no DS-pipe traffic).
template <int CTRL>
__device__ __forceinline__ float dppadd(float v) {
  int p = __builtin_amdgcn_update_dpp(0, __float_as_int(v), CTRL, 0xF, 0xF, true);
  return v + __int_as_float(p);
}

__device__ __forceinline__ float wsum64(float v) {
  v = dppadd<0xB1>(v);    // quad_perm {1,0,3,2}  : xor 1
  v = dppadd<0x4E>(v);    // quad_perm {2,3,0,1}  : xor 2
  v = dppadd<0x141>(v);   // row_half_mirror      : xor 7  -> 8-lane sums
  v = dppadd<0x140>(v);   // row_mirror           : xor 15 -> row (16) sums
  v = dppadd<0x142>(v);   // row_bcast15: row1 += row0, row3 += row2
  v = dppadd<0x143>(v);   // row_bcast31: rows 2,3 += (row0+row1); lane63 = total
  return __int_as_float(__builtin_amdgcn_readlane(__float_as_int(v), 63));
}

__device__ __forceinline__ v2f lo2(v4f a) { return __builtin_shufflevector(a, a, 0, 1); }
__device__ __forceinline__ v2f hi2(v4f a) { return __builtin_shufflevector(a, a, 2, 3); }

// One fused prep kernel (range-branched elementwise), 3851*256 = 985856:
//   [0,692224)        pose transpose -> posT[((n*32+o)*169+pix)*16 + d]
//   [692224,735488)   act transpose  -> actT[n][pix][o]
//   [735488,899328)   W coalesced    -> Wt3[((c*5+k)*4+q)*256 + lane*4 + j]
//   [899328,985856)   zero D0 and D1
__global__ __launch_bounds__(256) void prep_kernel(
    const float* __restrict__ x, const float* __restrict__ Wt,
    float* __restrict__ posT, float* __restrict__ actT,
    float* __restrict__ Wt3, float* __restrict__ Dz) {
  int tid = blockIdx.x * 256 + threadIdx.x;
  if (tid < 692224) {
    int pix = tid % 169; int t = tid / 169;
    int o = t & 31; t >>= 5;
    int d = t & 15; int n = t >> 4;
    float v = x[((size_t)n * 544 + d * 32 + o) * 169 + pix];
    posT[((size_t)(n * 32 + o) * 169 + pix) * 16 + d] = v;
  } else if (tid < 735488) {
    int r = tid - 692224;
    int pix = r % 169; int t = r / 169;
    int o = t & 31; int n = t >> 5;
    float v = x[(size_t)n * 91936 + 86528 + o * 169 + pix];
    actT[((size_t)n * 169 + pix) * 32 + o] = v;
  } else if (tid < 899328) {
    int r = tid - 735488;                     // 163840 = 32*5*4*256
    int j = r & 3;
    int lane = (r >> 2) & 63;
    int q = (r >> 8) & 3;
    int rem = r >> 10;                        // c*5 + k
    int k = rem % 5; int c = rem / 5;
    int ch = 64 * k + lane;
    Wt3[r] = (ch < 288) ? Wt[(size_t)ch * 512 + c * 16 + 4 * q + j] : 0.f;
  } else {
    Dz[tid - 899328] = 0.f;                   // D0 then D1 (contiguous)
  }
}

// Fused EM step, mode as template (DCE per phase).
// MODE 0: M(uniform Rp) + E -> p_hat, Dwrite
// MODE 1: M(p_hat, Dread) + E -> p_hat, Dwrite
// MODE 2: M(p_hat, Dread) -> final output
template <int MODE>
__global__ __launch_bounds__(256, 2) void em_kernel(
    const float* __restrict__ Wt3, const float* __restrict__ posT,
    const float* __restrict__ actT, float* __restrict__ p_hat,
    const float* __restrict__ Dread, float* __restrict__ Dwrite,
    const float* __restrict__ beta_v, const float* __restrict__ beta_a,
    const float* __restrict__ lambda_, float* __restrict__ out) {
  __shared__ float sP[288 * 20];   // pose patch, stride 20 (float4-aligned)
  __shared__ float sE[288];        // a/1152 or a/D per child slot
  __shared__ float sPh[4 * 288];   // per-wave p_hat by slot, for D reduce

  const int g = blockIdx.x & 7;        // c group
  const int sg = blockIdx.x >> 3;      // spatial 0..287
  const int wave = threadIdx.x >> 6;
  const int lane = threadIdx.x & 63;
  const int c = g * 4 + wave;

  int t = sg;
  const int y = t % 6; t /= 6;
  const int xx = t % 6;
  const int n = t / 6;

  const float bvv = beta_v[0], bav = beta_a[0], lamv = lambda_[0];
  const float* wbase = Wt3 + (size_t)c * 5120;   // [k][q][lane][4]

  // ---- prefetch p_hat (global, coalesced) so vmcnt overlaps staging ----
  float phv[5];
  if (MODE != 0) {
    const float* phb = p_hat + ((size_t)sg * 32 + c) * 288;
#pragma unroll
    for (int k = 0; k < 5; ++k) {
      int ch = lane + 64 * k; if (ch > 287) ch = 287;
      phv[k] = phb[ch];
    }
  }

  // ---- stage pose patch (coalesced float4) ----
  for (int task = threadIdx.x; task < 1152; task += 256) {
    int ch = task >> 2, q = task & 3;
    int o = ch & 31, ij = ch >> 5;
    int i = ij / 3, j = ij - i * 3;
    int pix = (2 * xx + i) * 13 + (2 * y + j);
    v4f v = *(const v4f*)(posT +
        ((size_t)((n * 32 + o) * 169) + pix) * 16 + q * 4);
    *(v4f*)(sP + ch * 20 + q * 4) = v;
  }
  // ---- stage rhat scale: a/1152 or a/D (32-contiguous reads) ----
  for (int task = threadIdx.x; task < 288; task += 256) {
    int o = task & 31, ij = task >> 5;
    int i = ij / 3, j = ij - i * 3;
    int idx = ((size_t)n * 169 + (2 * xx + i) * 13 + (2 * y + j)) * 32 + o;
    float a = actT[idx];
    sE[task] = (MODE == 0) ? a * (1.0f / 1152.0f) : a / Dread[idx];
  }
  __syncthreads();

  // ---- M step: packed float2 accumulation; W reads lane-contiguous ----
  float sum_r = 0.f;
  v2f sv2[8], sq2[8];
#pragma unroll
  for (int d = 0; d < 8; ++d) { sv2[d] = 0.f; sq2[d] = 0.f; }

#pragma unroll
  for (int k = 0; k < 5; ++k) {
    int ch = lane + 64 * k;
    const bool act_l = (ch < 288);
    const int chm = act_l ? ch : 0;

    const v4f* Pp = (const v4f*)(sP + chm * 20);
    v4f P0 = Pp[0], P1 = Pp[1], P2 = Pp[2], P3 = Pp[3];
    const v4f* Wq = (const v4f*)(wbase + k * 1024);   // 256 v4f per k
    v4f W0 = Wq[lane], W1 = Wq[64 + lane], W2 = Wq[128 + lane], W3 = Wq[192 + lane];

    float rhat = sE[chm];
    if (MODE != 0) rhat *= phv[k];
    if (!act_l) rhat = 0.f;
    sum_r += rhat;

    v2f PL0 = lo2(P0), PH0 = hi2(P0), PL1 = lo2(P1), PH1 = hi2(P1);
    v2f PL2 = lo2(P2), PH2 = hi2(P2), PL3 = lo2(P3), PH3 = hi2(P3);
    v2f r2 = rhat;

#pragma unroll
    for (int p = 0; p < 4; ++p) {
      v4f Wr = (p == 0) ? W0 : (p == 1) ? W1 : (p == 2) ? W2 : W3;
      v2f vlo = Wr.x * PL0 + Wr.y * PL1 + Wr.z * PL2 + Wr.w * PL3;
      v2f vhi = Wr.x * PH0 + Wr.y * PH1 + Wr.z * PH2 + Wr.w * PH3;
      v2f tlo = r2 * vlo, thi = r2 * vhi;
      sv2[p * 2 + 0] += tlo;
      sv2[p * 2 + 1] += thi;
      sq2[p * 2 + 0] += tlo * vlo;
      sq2[p * 2 + 1] += thi * vhi;
    }
  }

  sum_r = wsum64(sum_r);
  const float inv_sr = 1.0f / sum_r;
  float mu[16];
  float lsum = 0.f;
  float prod = 1.f;
#pragma unroll
  for (int d = 0; d < 16; ++d) {
    float s1 = wsum64(sv2[d >> 1][d & 1]);
    float s2 = wsum64(sq2[d >> 1][d & 1]);
    float m = s1 * inv_sr;
    mu[d] = m;
    float sg_ = fmaxf(s2 * inv_sr - m * m, 1e-30f);
    prod *= sg_;
    if ((d & 3) == 3) { lsum += __logf(prod); prod = 1.f; }
  }
  const float cost = (16.f * bvv + lsum) * sum_r;
  const float aout = 1.0f / (1.0f + __expf(-lamv * (bav - cost)));

  if (MODE == 2) {
    if (lane == 0) {
      float* ob = out + (size_t)(n * 544 + c * 16) * 36 + xx * 6 + y;
#pragma unroll
      for (int d = 0; d < 16; ++d) ob[d * 36] = mu[d];
      out[(size_t)(n * 544 + 512 + c) * 36 + xx * 6 + y] = aout;
    }
    return;
  }

  // ---- E step: recompute votes (packed), store to kperm'd slot ----
  v2f mu2[8];
#pragma unroll
  for (int d = 0; d < 8; ++d) { mu2[d].x = mu[2 * d]; mu2[d].y = mu[2 * d + 1]; }
  const float G = __logf(aout) - 0.5f * (lsum + 16.f * 1.8378770664093453f);

#pragma unroll
  for (int k = 0; k < 5; ++k) {
    int mch = lane + 64 * k;
    if (mch < 288) {
      const v4f* Pp = (const v4f*)(sP + mch * 20);
      v4f P0 = Pp[0], P1 = Pp[1], P2 = Pp[2], P3 = Pp[3];
      const v4f* Wq = (const v4f*)(wbase + k * 1024);
      v4f W0 = Wq[lane], W1 = Wq[64 + lane], W2 = Wq[128 + lane], W3 = Wq[192 + lane];

      v2f PL0 = lo2(P0), PH0 = hi2(P0), PL1 = lo2(P1), PH1 = hi2(P1);
      v2f PL2 = lo2(P2), PH2 = hi2(P2), PL3 = lo2(P3), PH3 = hi2(P3);
      v2f ss2 = 0.f;
#pragma unroll
      for (int p = 0; p < 4; ++p) {
        v4f Wr = (p == 0) ? W0 : (p == 1) ? W1 : (p == 2) ? W2 : W3;
        v2f vlo = Wr.x * PL0 + Wr.y * PL1 + Wr.z * PL2 + Wr.w * PL3;
        v2f vhi = Wr.x * PH0 + Wr.y * PH1 + Wr.z * PH2 + Wr.w * PH3;
        v2f dlo = vlo - mu2[p * 2 + 0];
        v2f dhi = vhi - mu2[p * 2 + 1];
        ss2 += dlo * dlo;
        ss2 += dhi * dhi;
      }
      float ss = ss2.x + ss2.y;
      float ph = __expf(G - ss);
      int o = mch & 31, ijm = mch >> 5;
      int im = ijm / 3, jm = ijm - im * 3;
      int i2 = (im == 0) ? 0 : 3 - im;   // kperm = {0,2,1}, involution
      int j2 = (jm == 0) ? 0 : 3 - jm;
      int slot = (i2 * 3 + j2) * 32 + o;
      p_hat[((size_t)sg * 32 + c) * 288 + slot] = ph;
      sPh[wave * 288 + slot] = ph;
    }
  }
  __syncthreads();
  // D reduce over block's 4 c + global atomic (8 c-grp blocks contribute)
  for (int t2 = threadIdx.x; t2 < 288; t2 += 256) {
    float s = sPh[t2] + sPh[288 + t2] + sPh[576 + t2] + sPh[864 + t2];
    int o = t2 & 31, ij = t2 >> 5;
    int i = ij / 3, j = ij - i * 3;
    atomicAdd(Dwrite + ((size_t)n * 169 + (2 * xx + i) * 13 + (2 * y + j)) * 32 + o, s);
  }
}

extern "C" void kernel_launch(void* const* d_in, const int* in_sizes, int n_in,
                              void* d_out, int out_size, void* d_ws,
                              size_t ws_size, hipStream_t stream) {
  const float* x   = (const float*)d_in[0];
  const float* Wt  = (const float*)d_in[1];
  const float* bv  = (const float*)d_in[2];
  const float* ba  = (const float*)d_in[3];
  const float* lam = (const float*)d_in[4];
  float* out = (float*)d_out;
  float* ws = (float*)d_ws;

  float* p_hat = ws + OFF_PHAT;
  float* D0    = ws + OFF_D0;
  float* D1    = ws + OFF_D1;
  float* posT  = ws + OFF_POST;
  float* actT  = ws + OFF_ACTT;
  float* Wt3   = ws + OFF_WT3;

  (void)in_sizes; (void)n_in; (void)out_size; (void)ws_size;

  // fused prep: transposes + coalesced W + zero D0/D1
  prep_kernel<<<3851, 256, 0, stream>>>(x, Wt, posT, actT, Wt3, D0);

  // M0 + E1 -> p_hat, D0
  em_kernel<0><<<2304, 256, 0, stream>>>(Wt3, posT, actT, p_hat, D1, D0,
                                         bv, ba, lam, out);
  // M1 (p_hat, D0) + E2 -> p_hat, D1
  em_kernel<1><<<2304, 256, 0, stream>>>(Wt3, posT, actT, p_hat, D0, D1,
                                         bv, ba, lam, out);
  // M2 (p_hat, D1) -> out
  em_kernel<2><<<2304, 256, 0, stream>>>(Wt3, posT, actT, p_hat, D1, D0,
                                         bv, ba, lam, out);
}

// Round 11
// 136.284 us; speedup vs baseline: 2.8404x; 1.0509x over previous
//
#include <hip/hip_runtime.h>

// ---------------------------------------------------------------------------
// ConvCaps (EM routing): b=8, B=32, C=32, K=3, stride=2, Win=13, Wout=6, 3 iters
// x: (8, 544, 13, 13) f32   [pose 512ch = (q,r,o), act 32ch]
// W: (3,3,32,32,4,4) f32    [ch=(ij*32+o)][c][p][q], 512 floats per ch
// out: (8, 544, 6, 6) f32
// vote[d=p*4+r] = sum_q W[ch][c][p][q] * pose[n,q,r,o, 2x+i, 2y+j]
//
// R21 = R20 (143us: 3-launch, 256thr/4-wave, grid 2304, sP staging, DPP
// reductions, TA-coalesced Wt3) + VOTES CACHED IN VGPR ACROSS M->E:
//   v2f vo[40] (80 VGPR) holds all votes; E step drops its W reload
//   (20 v4f = 320 TA lines), P reload (20 LDS v4f) and ~240 pk-FMA vote
//   recompute -> E is pure register math + exp + store.
//   __launch_bounds__(256) with NO occupancy arg -> VGPR cap 256 ->
//   spill-impossible by construction (peak live ~160). Occupancy ~12
//   waves/CU; R13 proved 20<->32 neutral, and this cut shortens the
//   per-wave serial path that low occupancy would expose.
// Evidence: both real wins (R11 DPP -14us, R20 W-coalesce -12us) came from
// deleting per-wave work; TLP/ILP/occupancy all neutral. E-step reload+
// recompute was the largest remaining per-wave block (~35% instrs, ~50% TA).
// Session rules: spin barriers + coop launch BANNED (R16-18). launch-bounds
// arg2 = blocks/CU -> cap 256/arg2@512thr, 128@(256,2); NO arg = cap 256.
// Spill symptom: WRITE_SIZE x20 (R12/R14). Template MODE: mode-2 DCEs vo.
// p_hat block-private; only D crosses blocks -> ping-pong D0/D1.
// ---------------------------------------------------------------------------

typedef float v2f __attribute__((ext_vector_type(2)));
typedef float v4f __attribute__((ext_vector_type(4)));

// workspace layout (floats)
#define OFF_PHAT 0           // 288*32*288 = 2654208   [spatial][c][slot]
#define OFF_D0   2654208     // 43264 = 8*169*32   [n][pix][o]
#define OFF_D1   2697472     // 43264
#define OFF_POST 2740736     // 692224 = 8*32*169*16   [(n,o)][pix][d]
#define OFF_ACTT 3432960     // 43264  [n][pix][o]
#define OFF_WT3  3476224     // 163840 = 32*5*4*256  [c][k][q][lane][4]
// total 3640064 floats = 14.6 MB

// DPP butterfly-reduce on the VALU pipe (no DS-pipe traffic).
template <int CTRL>
__device__ __forceinline__ float dppadd(float v) {
  int p = __builtin_amdgcn_update_dpp(0, __float_as_int(v), CTRL, 0xF, 0xF, true);
  return v + __int_as_float(p);
}

__device__ __forceinline__ float wsum64(float v) {
  v = dppadd<0xB1>(v);    // quad_perm {1,0,3,2}  : xor 1
  v = dppadd<0x4E>(v);    // quad_perm {2,3,0,1}  : xor 2
  v = dppadd<0x141>(v);   // row_half_mirror      : xor 7  -> 8-lane sums
  v = dppadd<0x140>(v);   // row_mirror           : xor 15 -> row (16) sums
  v = dppadd<0x142>(v);   // row_bcast15: row1 += row0, row3 += row2
  v = dppadd<0x143>(v);   // row_bcast31: rows 2,3 += (row0+row1); lane63 = total
  return __int_as_float(__builtin_amdgcn_readlane(__float_as_int(v), 63));
}

__device__ __forceinline__ v2f lo2(v4f a) { return __builtin_shufflevector(a, a, 0, 1); }
__device__ __forceinline__ v2f hi2(v4f a) { return __builtin_shufflevector(a, a, 2, 3); }

// One fused prep kernel (range-branched elementwise), 3851*256 = 985856:
//   [0,692224)        pose transpose -> posT[((n*32+o)*169+pix)*16 + d]
//   [692224,735488)   act transpose  -> actT[n][pix][o]
//   [735488,899328)   W coalesced    -> Wt3[((c*5+k)*4+q)*256 + lane*4 + j]
//   [899328,985856)   zero D0 and D1
__global__ __launch_bounds__(256) void prep_kernel(
    const float* __restrict__ x, const float* __restrict__ Wt,
    float* __restrict__ posT, float* __restrict__ actT,
    float* __restrict__ Wt3, float* __restrict__ Dz) {
  int tid = blockIdx.x * 256 + threadIdx.x;
  if (tid < 692224) {
    int pix = tid % 169; int t = tid / 169;
    int o = t & 31; t >>= 5;
    int d = t & 15; int n = t >> 4;
    float v = x[((size_t)n * 544 + d * 32 + o) * 169 + pix];
    posT[((size_t)(n * 32 + o) * 169 + pix) * 16 + d] = v;
  } else if (tid < 735488) {
    int r = tid - 692224;
    int pix = r % 169; int t = r / 169;
    int o = t & 31; int n = t >> 5;
    float v = x[(size_t)n * 91936 + 86528 + o * 169 + pix];
    actT[((size_t)n * 169 + pix) * 32 + o] = v;
  } else if (tid < 899328) {
    int r = tid - 735488;                     // 163840 = 32*5*4*256
    int j = r & 3;
    int lane = (r >> 2) & 63;
    int q = (r >> 8) & 3;
    int rem = r >> 10;                        // c*5 + k
    int k = rem % 5; int c = rem / 5;
    int ch = 64 * k + lane;
    Wt3[r] = (ch < 288) ? Wt[(size_t)ch * 512 + c * 16 + 4 * q + j] : 0.f;
  } else {
    Dz[tid - 899328] = 0.f;                   // D0 then D1 (contiguous)
  }
}

// Fused EM step, mode as template (DCE per phase).
// MODE 0: M(uniform Rp) + E -> p_hat, Dwrite
// MODE 1: M(p_hat, Dread) + E -> p_hat, Dwrite
// MODE 2: M(p_hat, Dread) -> final output
template <int MODE>
__global__ __launch_bounds__(256) void em_kernel(
    const float* __restrict__ Wt3, const float* __restrict__ posT,
    const float* __restrict__ actT, float* __restrict__ p_hat,
    const float* __restrict__ Dread, float* __restrict__ Dwrite,
    const float* __restrict__ beta_v, const float* __restrict__ beta_a,
    const float* __restrict__ lambda_, float* __restrict__ out) {
  __shared__ float sP[288 * 20];   // pose patch, stride 20 (float4-aligned)
  __shared__ float sE[288];        // a/1152 or a/D per child slot
  __shared__ float sPh[4 * 288];   // per-wave p_hat by slot, for D reduce

  const int g = blockIdx.x & 7;        // c group
  const int sg = blockIdx.x >> 3;      // spatial 0..287
  const int wave = threadIdx.x >> 6;
  const int lane = threadIdx.x & 63;
  const int c = g * 4 + wave;

  int t = sg;
  const int y = t % 6; t /= 6;
  const int xx = t % 6;
  const int n = t / 6;

  const float bvv = beta_v[0], bav = beta_a[0], lamv = lambda_[0];
  const float* wbase = Wt3 + (size_t)c * 5120;   // [k][q][lane][4]

  // ---- prefetch p_hat (global, coalesced) so vmcnt overlaps staging ----
  float phv[5];
  if (MODE != 0) {
    const float* phb = p_hat + ((size_t)sg * 32 + c) * 288;
#pragma unroll
    for (int k = 0; k < 5; ++k) {
      int ch = lane + 64 * k; if (ch > 287) ch = 287;
      phv[k] = phb[ch];
    }
  }

  // ---- stage pose patch (coalesced float4) ----
  for (int task = threadIdx.x; task < 1152; task += 256) {
    int ch = task >> 2, q = task & 3;
    int o = ch & 31, ij = ch >> 5;
    int i = ij / 3, j = ij - i * 3;
    int pix = (2 * xx + i) * 13 + (2 * y + j);
    v4f v = *(const v4f*)(posT +
        ((size_t)((n * 32 + o) * 169) + pix) * 16 + q * 4);
    *(v4f*)(sP + ch * 20 + q * 4) = v;
  }
  // ---- stage rhat scale: a/1152 or a/D (32-contiguous reads) ----
  for (int task = threadIdx.x; task < 288; task += 256) {
    int o = task & 31, ij = task >> 5;
    int i = ij / 3, j = ij - i * 3;
    int idx = ((size_t)n * 169 + (2 * xx + i) * 13 + (2 * y + j)) * 32 + o;
    float a = actT[idx];
    sE[task] = (MODE == 0) ? a * (1.0f / 1152.0f) : a / Dread[idx];
  }
  __syncthreads();

  // ---- M step: packed float2 accumulation; votes cached in VGPR ----
  float sum_r = 0.f;
  v2f sv2[8], sq2[8];
  v2f vo[40];   // [k][p*2+half] votes, static-indexed after unroll (80 VGPR)
#pragma unroll
  for (int d = 0; d < 8; ++d) { sv2[d] = 0.f; sq2[d] = 0.f; }

#pragma unroll
  for (int k = 0; k < 5; ++k) {
    int ch = lane + 64 * k;
    const bool act_l = (ch < 288);
    const int chm = act_l ? ch : 0;

    const v4f* Pp = (const v4f*)(sP + chm * 20);
    v4f P0 = Pp[0], P1 = Pp[1], P2 = Pp[2], P3 = Pp[3];
    const v4f* Wq = (const v4f*)(wbase + k * 1024);   // 256 v4f per k
    v4f W0 = Wq[lane], W1 = Wq[64 + lane], W2 = Wq[128 + lane], W3 = Wq[192 + lane];

    float rhat = sE[chm];
    if (MODE != 0) rhat *= phv[k];
    if (!act_l) rhat = 0.f;
    sum_r += rhat;

    v2f PL0 = lo2(P0), PH0 = hi2(P0), PL1 = lo2(P1), PH1 = hi2(P1);
    v2f PL2 = lo2(P2), PH2 = hi2(P2), PL3 = lo2(P3), PH3 = hi2(P3);
    v2f r2 = rhat;

#pragma unroll
    for (int p = 0; p < 4; ++p) {
      v4f Wr = (p == 0) ? W0 : (p == 1) ? W1 : (p == 2) ? W2 : W3;
      v2f vlo = Wr.x * PL0 + Wr.y * PL1 + Wr.z * PL2 + Wr.w * PL3;
      v2f vhi = Wr.x * PH0 + Wr.y * PH1 + Wr.z * PH2 + Wr.w * PH3;
      vo[k * 8 + p * 2 + 0] = vlo;
      vo[k * 8 + p * 2 + 1] = vhi;
      v2f tlo = r2 * vlo, thi = r2 * vhi;
      sv2[p * 2 + 0] += tlo;
      sv2[p * 2 + 1] += thi;
      sq2[p * 2 + 0] += tlo * vlo;
      sq2[p * 2 + 1] += thi * vhi;
    }
  }

  sum_r = wsum64(sum_r);
  const float inv_sr = 1.0f / sum_r;
  float mu[16];
  float lsum = 0.f;
  float prod = 1.f;
#pragma unroll
  for (int d = 0; d < 16; ++d) {
    float s1 = wsum64(sv2[d >> 1][d & 1]);
    float s2 = wsum64(sq2[d >> 1][d & 1]);
    float m = s1 * inv_sr;
    mu[d] = m;
    float sg_ = fmaxf(s2 * inv_sr - m * m, 1e-30f);
    prod *= sg_;
    if ((d & 3) == 3) { lsum += __logf(prod); prod = 1.f; }
  }
  const float cost = (16.f * bvv + lsum) * sum_r;
  const float aout = 1.0f / (1.0f + __expf(-lamv * (bav - cost)));

  if (MODE == 2) {
    if (lane == 0) {
      float* ob = out + (size_t)(n * 544 + c * 16) * 36 + xx * 6 + y;
#pragma unroll
      for (int d = 0; d < 16; ++d) ob[d * 36] = mu[d];
      out[(size_t)(n * 544 + 512 + c) * 36 + xx * 6 + y] = aout;
    }
    return;
  }

  // ---- E step: pure register math on cached votes, store kperm'd ----
  v2f mu2[8];
#pragma unroll
  for (int d = 0; d < 8; ++d) { mu2[d].x = mu[2 * d]; mu2[d].y = mu[2 * d + 1]; }
  const float G = __logf(aout) - 0.5f * (lsum + 16.f * 1.8378770664093453f);

#pragma unroll
  for (int k = 0; k < 5; ++k) {
    int mch = lane + 64 * k;
    if (mch < 288) {
      v2f ss2 = 0.f;
#pragma unroll
      for (int p = 0; p < 4; ++p) {
        v2f dlo = vo[k * 8 + p * 2 + 0] - mu2[p * 2 + 0];
        v2f dhi = vo[k * 8 + p * 2 + 1] - mu2[p * 2 + 1];
        ss2 += dlo * dlo;
        ss2 += dhi * dhi;
      }
      float ss = ss2.x + ss2.y;
      float ph = __expf(G - ss);
      int o = mch & 31, ijm = mch >> 5;
      int im = ijm / 3, jm = ijm - im * 3;
      int i2 = (im == 0) ? 0 : 3 - im;   // kperm = {0,2,1}, involution
      int j2 = (jm == 0) ? 0 : 3 - jm;
      int slot = (i2 * 3 + j2) * 32 + o;
      p_hat[((size_t)sg * 32 + c) * 288 + slot] = ph;
      sPh[wave * 288 + slot] = ph;
    }
  }
  __syncthreads();
  // D reduce over block's 4 c + global atomic (8 c-grp blocks contribute)
  for (int t2 = threadIdx.x; t2 < 288; t2 += 256) {
    float s = sPh[t2] + sPh[288 + t2] + sPh[576 + t2] + sPh[864 + t2];
    int o = t2 & 31, ij = t2 >> 5;
    int i = ij / 3, j = ij - i * 3;
    atomicAdd(Dwrite + ((size_t)n * 169 + (2 * xx + i) * 13 + (2 * y + j)) * 32 + o, s);
  }
}

extern "C" void kernel_launch(void* const* d_in, const int* in_sizes, int n_in,
                              void* d_out, int out_size, void* d_ws,
                              size_t ws_size, hipStream_t stream) {
  const float* x   = (const float*)d_in[0];
  const float* Wt  = (const float*)d_in[1];
  const float* bv  = (const float*)d_in[2];
  const float* ba  = (const float*)d_in[3];
  const float* lam = (const float*)d_in[4];
  float* out = (float*)d_out;
  float* ws = (float*)d_ws;

  float* p_hat = ws + OFF_PHAT;
  float* D0    = ws + OFF_D0;
  float* D1    = ws + OFF_D1;
  float* posT  = ws + OFF_POST;
  float* actT  = ws + OFF_ACTT;
  float* Wt3   = ws + OFF_WT3;

  (void)in_sizes; (void)n_in; (void)out_size; (void)ws_size;

  // fused prep: transposes + coalesced W + zero D0/D1
  prep_kernel<<<3851, 256, 0, stream>>>(x, Wt, posT, actT, Wt3, D0);

  // M0 + E1 -> p_hat, D0
  em_kernel<0><<<2304, 256, 0, stream>>>(Wt3, posT, actT, p_hat, D1, D0,
                                         bv, ba, lam, out);
  // M1 (p_hat, D0) + E2 -> p_hat, D1
  em_kernel<1><<<2304, 256, 0, stream>>>(Wt3, posT, actT, p_hat, D0, D1,
                                         bv, ba, lam, out);
  // M2 (p_hat, D1) -> out
  em_kernel<2><<<2304, 256, 0, stream>>>(Wt3, posT, actT, p_hat, D1, D0,
                                         bv, ba, lam, out);
}